// Round 5
// baseline (246.440 us; speedup 1.0000x reference)
//
#include <hip/hip_runtime.h>
#include <stdint.h>

#define NL      8192
#define NH      32768
#define FDIM    128
#define KSEL    32
#define QPW     4                 // queries per wave
#define NWAVES  2
#define BLOCK   (NWAVES * 64)     // 128
#define QPB     (NWAVES * QPW)    // 8 queries per block
#define BUFCAP  256
#define NGROUP  (NL / 64)         // 128 groups of 64 sorted points
#define NCELL   4096              // 16^3 Morton cells
#define TSCAN   4                 // nearest groups scanned for tau
#define MAXPASS 6
#define PRE_T   1024

__device__ __forceinline__ int imin(int a, int b) { return a < b ? a : b; }
__device__ __forceinline__ int imax(int a, int b) { return a > b ? a : b; }

// ---- ballot rank-select: smallest nonneg int key t with count(keys<=t)>=rank.
// Keys must be >= 0 (float bits of nonneg floats / packed nonneg). Invalid
// slots hold 0x7F800000 (inf) which is never counted (mid < hi always).
__device__ __forceinline__ int rank_select1(int k0, int rank) {
    unsigned lo = 0u, hi = 0x7F800000u;
    while (lo < hi) {
        const int mid = (int)((lo + hi) >> 1);
        const int cnt = (int)__popcll(__ballot(k0 <= mid));
        if (cnt >= rank) hi = (unsigned)mid; else lo = (unsigned)mid + 1u;
    }
    return (int)lo;
}
__device__ __forceinline__ int rank_select2(int k0, int k1, int rank) {
    unsigned lo = 0u, hi = 0x7F800000u;
    while (lo < hi) {
        const int mid = (int)((lo + hi) >> 1);
        const int cnt = (int)__popcll(__ballot(k0 <= mid))
                      + (int)__popcll(__ballot(k1 <= mid));
        if (cnt >= rank) hi = (unsigned)mid; else lo = (unsigned)mid + 1u;
    }
    return (int)lo;
}
__device__ __forceinline__ int rank_select4(const int* k, int rank) {
    unsigned lo = 0u, hi = 0x7F800000u;
    while (lo < hi) {
        const int mid = (int)((lo + hi) >> 1);
        int cnt = 0;
#pragma unroll
        for (int r = 0; r < 4; ++r)
            cnt += (int)__popcll(__ballot(k[r] <= mid));
        if (cnt >= rank) hi = (unsigned)mid; else lo = (unsigned)mid + 1u;
    }
    return (int)lo;
}

// ---- Morton cell id: 16^3 grid over [-4,4], cell size 0.5 ----
__device__ __forceinline__ uint32_t spread3(uint32_t x) {
    x &= 0xFu;
    x = (x | (x << 16)) & 0x030000FFu;
    x = (x | (x << 8))  & 0x0300F00Fu;
    x = (x | (x << 4))  & 0x030C30C3u;
    x = (x | (x << 2))  & 0x09249249u;
    return x;
}
__device__ __forceinline__ int cell_of(float px, float py, float pz) {
    int ix = (int)floorf((px + 4.0f) * 2.0f);
    int iy = (int)floorf((py + 4.0f) * 2.0f);
    int iz = (int)floorf((pz + 4.0f) * 2.0f);
    ix = imin(imax(ix, 0), 15); iy = imin(imax(iy, 0), 15); iz = imin(imax(iz, 0), 15);
    return (int)(spread3((uint32_t)ix) | (spread3((uint32_t)iy) << 1) | (spread3((uint32_t)iz) << 2));
}

// =============== Fused preprocessing: 1 block, 1024 threads ===============
// histogram (LDS atomics) -> scan (wave shfl) -> scatter -> group spheres
__global__ __launch_bounds__(PRE_T)
void k_preprocess(const float* __restrict__ pos_l,
                  float4* __restrict__ sorted, int* __restrict__ oidx,
                  float4* __restrict__ spheres)
{
    __shared__ int hist[NCELL];          // 16 KB; becomes cursor after scan
    __shared__ int wpart[PRE_T / 64];    // per-wave totals
    const int tid  = threadIdx.x;
    const int lane = tid & 63;
    const int wv   = tid >> 6;

    for (int i = tid; i < NCELL; i += PRE_T) hist[i] = 0;
    __syncthreads();

    // histogram: 8 points per thread (coalesced reads of pos_l)
    int cc[8]; float px[8], py[8], pz[8];
#pragma unroll
    for (int r = 0; r < 8; ++r) {
        const int i = r * PRE_T + tid;
        px[r] = pos_l[i * 3 + 0];
        py[r] = pos_l[i * 3 + 1];
        pz[r] = pos_l[i * 3 + 2];
        cc[r] = cell_of(px[r], py[r], pz[r]);
        atomicAdd(&hist[cc[r]], 1);
    }
    __syncthreads();

    // exclusive scan over 4096 cells: thread owns cells [4*tid, 4*tid+4)
    int loc[4]; int ts = 0;
#pragma unroll
    for (int i = 0; i < 4; ++i) { loc[i] = ts; ts += hist[tid * 4 + i]; }
    int incl = ts;
#pragma unroll
    for (int d = 1; d < 64; d <<= 1) {
        const int t = __shfl_up(incl, d);
        if (lane >= d) incl += t;
    }
    if (lane == 63) wpart[wv] = incl;
    __syncthreads();
    int base = 0;
    for (int j = 0; j < wv; ++j) base += wpart[j];
    const int texcl = base + incl - ts;
#pragma unroll
    for (int i = 0; i < 4; ++i) hist[tid * 4 + i] = texcl + loc[i];  // own cells only
    __syncthreads();

    // scatter into cell-sorted order
#pragma unroll
    for (int r = 0; r < 8; ++r) {
        const int pos = atomicAdd(&hist[cc[r]], 1);
        sorted[pos] = make_float4(px[r], py[r], pz[r],
                                  fmaf(px[r], px[r], fmaf(py[r], py[r], pz[r] * pz[r])));
        oidx[pos] = r * PRE_T + tid;
    }
    __syncthreads();   // block-scope visibility of the global writes

    // bounding spheres: 16 waves x 8 groups
#pragma unroll
    for (int r = 0; r < NGROUP / (PRE_T / 64); ++r) {
        const int g = wv * (NGROUP / (PRE_T / 64)) + r;
        const float4 p = sorted[g * 64 + lane];
        float sx = p.x, sy = p.y, sz = p.z;
#pragma unroll
        for (int j = 32; j >= 1; j >>= 1) {
            sx += __shfl_xor(sx, j); sy += __shfl_xor(sy, j); sz += __shfl_xor(sz, j);
        }
        const float cx = sx * (1.0f / 64.0f), cy = sy * (1.0f / 64.0f), cz = sz * (1.0f / 64.0f);
        const float dx = p.x - cx, dy = p.y - cy, dz = p.z - cz;
        float d2 = fmaf(dx, dx, fmaf(dy, dy, dz * dz));
#pragma unroll
        for (int j = 32; j >= 1; j >>= 1) d2 = fmaxf(d2, __shfl_xor(d2, j));
        if (lane == 0) spheres[g] = make_float4(cx, cy, cz, sqrtf(d2) + 1e-3f);
    }
}

// =================== Main kernel ===================
__global__ __launch_bounds__(BLOCK, 6)
void knn_interp_kernel(const float* __restrict__ x,
                       const float* __restrict__ pos_h,
                       const float4* __restrict__ sorted,
                       const float4* __restrict__ spheres,
                       const int* __restrict__ oidx,
                       float* __restrict__ out)
{
    __shared__ uint16_t s_idx[QPB][BUFCAP];                // 4 KB
    __shared__ float    s_w[QPB][KSEL];                    // 1 KB
    __shared__ int      s_wi[QPB][KSEL];                   // 1 KB
    __shared__ unsigned long long s_surv[NWAVES][QPW][2];  // 128 B

    const int tid   = threadIdx.x;
    const int lane  = tid & 63;
    const int wid   = tid >> 6;
    const int qbase = blockIdx.x * QPB + wid * QPW;
    const unsigned long long mlt = (1ull << lane) - 1ull;  // bits strictly below lane

    // lane owns group `lane` (A) and `lane+64` (B); kept in registers
    const float4 cA = spheres[lane];
    const float4 cB = spheres[lane + 64];

    float qx[QPW], qy[QPW], qz[QPW], h2q[QPW], tauD[QPW];

    // ---- Phase 1: tau per query (4 nearest groups via ballot rank-select,
    //      256-pt scan, 32nd-smallest via ballot rank-select) + sphere masks ----
#pragma unroll
    for (int q = 0; q < QPW; ++q) {
        const int gq = qbase + q;
        const float ax = pos_h[gq * 3 + 0];
        const float ay = pos_h[gq * 3 + 1];
        const float az = pos_h[gq * 3 + 2];
        qx[q] = ax; qy[q] = ay; qz[q] = az;
        const float h2 = fmaf(ax, ax, fmaf(ay, ay, az * az));
        h2q[q] = h2;

        const float dAx = ax - cA.x, dAy = ay - cA.y, dAz = az - cA.z;
        const float dA  = fmaf(dAx, dAx, fmaf(dAy, dAy, dAz * dAz));
        const float dBx = ax - cB.x, dBy = ay - cB.y, dBz = az - cB.z;
        const float dB  = fmaf(dBx, dBx, fmaf(dBy, dBy, dBz * dBz));

        // packed keys: (d2c top 24 bits | group id). ids unique -> exactly
        // TSCAN keys <= t4, and the ballot bits ARE the selected group ids.
        const int kA = (int)((__float_as_uint(dA) & 0xFFFFFF00u) | (uint32_t)lane);
        const int kB = (int)((__float_as_uint(dB) & 0xFFFFFF00u) | (uint32_t)(lane + 64));
        const int t4 = rank_select2(kA, kB, TSCAN);
        unsigned long long gm0 = __ballot(kA <= t4);
        unsigned long long gm1 = __ballot(kB <= t4);

        // scan the 4*64 = 256 nearest-ish points; per-lane min of D = |p|^2-2q.p
        float dmin = INFINITY;
#pragma unroll 1
        for (int t = 0; t < TSCAN; ++t) {
            int g;
            if (gm0) { g = __builtin_ctzll(gm0); gm0 &= gm0 - 1ull; }
            else     { g = 64 + __builtin_ctzll(gm1); gm1 &= gm1 - 1ull; }
            const float4 p = sorted[(g << 6) + lane];
            const float s = fmaf(ax, p.x, fmaf(ay, p.y, az * p.z));
            dmin = fminf(dmin, fmaf(-2.0f, s, p.w));
        }
        // 32nd smallest lane-min >= true 32nd d2 (>=32 distinct points below it)
        const float d2min = fmaxf(dmin + h2, 0.0f);
        const int t32 = rank_select1(__float_as_int(d2min), KSEL);
        const float tau_d2 = __int_as_float(t32) + 1e-4f;
        tauD[q] = tau_d2 - h2;                 // D-space threshold (R4-verified margin)
        const float st = sqrtf(tau_d2) + 1e-3f;
        const float tA = st + cA.w, tB = st + cB.w;
        const unsigned long long bA = __ballot(dA <= tA * tA);
        const unsigned long long bB = __ballot(dB <= tB * tB);
        if (lane == 0) { s_surv[wid][q][0] = bA; s_surv[wid][q][1] = bB; }
    }

    // ---- Phase 2: per query: prefetched collect (w/ overflow tightening) ->
    //      exact fp64 re-rank -> top-32 -> gather + weighted average ----
#pragma unroll 1
    for (int q = 0; q < QPW; ++q) {
        const int QQ = wid * QPW + q;
        const int gq = qbase + q;
        const float ax = qx[q], ay = qy[q], az = qz[q];
        float tau = tauD[q];
        int M = 0;

#pragma unroll 1
        for (int pass = 0; pass < MAXPASS; ++pass) {
            M = 0;
            unsigned long long m0 = s_surv[wid][q][0];
            unsigned long long m1 = s_surv[wid][q][1];
            int g_cur = -1;
            if (m0)      { g_cur = __builtin_ctzll(m0); m0 &= m0 - 1ull; }
            else if (m1) { g_cur = 64 + __builtin_ctzll(m1); m1 &= m1 - 1ull; }
            float4 pc = make_float4(0, 0, 0, 0);
            if (g_cur >= 0) pc = sorted[(g_cur << 6) + lane];
#pragma unroll 1
            while (g_cur >= 0) {
                // prefetch next group's points before the ballot sync point
                int g_nxt = -1;
                if (m0)      { g_nxt = __builtin_ctzll(m0); m0 &= m0 - 1ull; }
                else if (m1) { g_nxt = 64 + __builtin_ctzll(m1); m1 &= m1 - 1ull; }
                float4 pn = pc;
                if (g_nxt >= 0) pn = sorted[(g_nxt << 6) + lane];

                const float s = fmaf(ax, pc.x, fmaf(ay, pc.y, az * pc.z));
                const float D = fmaf(-2.0f, s, pc.w);
                const bool hit = (D <= tau);
                const unsigned long long b = __ballot(hit);
                if (b) {
                    const int o = M + (int)__popcll(b & mlt);
                    if (hit && o < BUFCAP) s_idx[QQ][o] = (uint16_t)((g_cur << 6) + lane);
                    M += (int)__popcll(b);
                }
                g_cur = g_nxt; pc = pn;
            }
            if (M <= BUFCAP) break;
            // overflow: tighten tau to exact 32nd-smallest d2 of the 256
            // buffered (order stat of a subset => still >= global 32nd).
            int kk[4];
#pragma unroll
            for (int r = 0; r < 4; ++r) {
                const int idx = (int)s_idx[QQ][64 * r + lane];
                const float4 c = sorted[idx];
                const float s = fmaf(ax, c.x, fmaf(ay, c.y, az * c.z));
                const float d2 = fmaxf(fmaf(-2.0f, s, c.w) + h2q[q], 0.0f);
                kk[r] = __float_as_int(d2);
            }
            const int tk = rank_select4(kk, KSEL);
            tau = __int_as_float(tk) + 1e-4f - h2q[q];   // back to D-space + margin
        }
        if (M > BUFCAP) M = BUFCAP;

        // -------- exact fp64 re-rank + top-32 selection (ballot-based) --------
        const double axd = (double)ax, ayd = (double)ay, azd = (double)az;
        if (M <= 128) {
            const int i0 = (2 * lane     < M) ? (int)s_idx[QQ][2 * lane]     : -1;
            const int i1 = (2 * lane + 1 < M) ? (int)s_idx[QQ][2 * lane + 1] : -1;
            float f0 = INFINITY, f1 = INFINITY;
            if (i0 >= 0) {
                const float4 c = sorted[i0];
                const double dx = (double)c.x - axd, dy = (double)c.y - ayd, dz = (double)c.z - azd;
                f0 = (float)(dx * dx + dy * dy + dz * dz);
            }
            if (i1 >= 0) {
                const float4 c = sorted[i1];
                const double dx = (double)c.x - axd, dy = (double)c.y - ayd, dz = (double)c.z - azd;
                f1 = (float)(dx * dx + dy * dy + dz * dz);
            }
            const int k0 = __float_as_int(f0), k1 = __float_as_int(f1);
            const int tau32 = rank_select2(k0, k1, KSEL);   // 32nd smallest value
            const bool a0 = (i0 >= 0) && (k0 <= tau32);
            const bool a1 = (i1 >= 0) && (k1 <= tau32);
            const unsigned long long b0 = __ballot(a0);
            const unsigned long long b1 = __ballot(a1);
            const int base = (int)__popcll(b0 & mlt) + (int)__popcll(b1 & mlt);
            const int p0 = base;
            const int p1 = base + (a0 ? 1 : 0);
            if (a0 && p0 < KSEL) { s_w[QQ][p0] = 1.0f / fmaxf(f0, 1e-16f); s_wi[QQ][p0] = oidx[i0]; }
            if (a1 && p1 < KSEL) { s_w[QQ][p1] = 1.0f / fmaxf(f1, 1e-16f); s_wi[QQ][p1] = oidx[i1]; }
        } else {
            // rare path (128 < M <= 256): 4 elems/lane
            int ii[4]; float ff[4]; int kk_[4];
#pragma unroll
            for (int r = 0; r < 4; ++r) {
                const int e = 4 * lane + r;
                ii[r] = (e < M) ? (int)s_idx[QQ][e] : -1;
                ff[r] = INFINITY;
                if (ii[r] >= 0) {
                    const float4 c = sorted[ii[r]];
                    const double dx = (double)c.x - axd, dy = (double)c.y - ayd, dz = (double)c.z - azd;
                    ff[r] = (float)(dx * dx + dy * dy + dz * dz);
                }
                kk_[r] = __float_as_int(ff[r]);
            }
            const int tau32 = rank_select4(kk_, KSEL);
            bool a[4]; unsigned long long b[4];
#pragma unroll
            for (int r = 0; r < 4; ++r) {
                a[r] = (ii[r] >= 0) && (kk_[r] <= tau32);
                b[r] = __ballot(a[r]);
            }
            int base = 0;
#pragma unroll
            for (int r = 0; r < 4; ++r) base += (int)__popcll(b[r] & mlt);
            int pref = 0;
#pragma unroll
            for (int r = 0; r < 4; ++r) {
                const int p = base + pref;
                if (a[r] && p < KSEL) { s_w[QQ][p] = 1.0f / fmaxf(ff[r], 1e-16f); s_wi[QQ][p] = oidx[ii[r]]; }
                pref += (a[r] ? 1 : 0);
            }
        }

        // -------- gather + inverse-d2 weighted average --------
        float acc0 = 0.0f, acc1 = 0.0f, wsum = 0.0f;
#pragma unroll 8
        for (int t = 0; t < KSEL; ++t) {
            const float w   = s_w[QQ][t];
            const int   idx = s_wi[QQ][t];
            const float* row = x + (size_t)idx * FDIM;
            acc0 = fmaf(w, row[lane], acc0);
            acc1 = fmaf(w, row[lane + 64], acc1);
            wsum += w;
        }
        const float invw = 1.0f / wsum;
        out[(size_t)gq * FDIM + lane]      = acc0 * invw;
        out[(size_t)gq * FDIM + 64 + lane] = acc1 * invw;
    }
}

extern "C" void kernel_launch(void* const* d_in, const int* in_sizes, int n_in,
                              void* d_out, int out_size, void* d_ws, size_t ws_size,
                              hipStream_t stream) {
    const float* x     = (const float*)d_in[0];
    const float* pos_l = (const float*)d_in[1];
    const float* pos_h = (const float*)d_in[2];
    float* out = (float*)d_out;

    char* ws = (char*)d_ws;
    float4* sorted  = (float4*)(ws + 0);        // 128 KB
    int*    oidx    = (int*)(ws + 131072);      // 32 KB
    float4* spheres = (float4*)(ws + 163840);   // 2 KB

    hipLaunchKernelGGL(k_preprocess, dim3(1), dim3(PRE_T), 0, stream,
                       pos_l, sorted, oidx, spheres);
    hipLaunchKernelGGL(knn_interp_kernel, dim3(NH / QPB), dim3(BLOCK), 0, stream,
                       x, pos_h, sorted, spheres, oidx, out);
}